// Round 7
// baseline (24302.617 us; speedup 1.0000x reference)
//
#include <hip/hip_runtime.h>
#include <cstdint>
#include <cstddef>

// ============================================================================
// Aligner (forward attention + GRU), persistent-kernel, MFMA-bf16 edition.
// Round 13: R11 structure (2 gbarriers + q mini-barrier, merged Phase 2),
// R12's spilling register-carry pipelining REVERTED, and every rendezvous
// flattened from two-hop (arrivals -> gatherer -> broadcast) to ONE round
// trip: 256 arrival flags packed into 16 contiguous lines, every block polls
// all 16 lines directly (64 threads x dwordx4, s_sleep-throttled). The q
// mini-barrier likewise: 32 packed producer flags, 8 polling threads/block.
// Rationale: R10->R11 showed barrier COUNT is nearly free, while wall time
// ~= (#serial agent-scope RTs ~16) x (RT ~1.4us). Flattening cuts 1 RT per
// rendezvous x 3 per step.
// Keeps R10/R11 wins: transposed TPART, ENC16 pu, merged Phase 2.
// ============================================================================

namespace cfg {
constexpr int NB = 32, NS = 256, NI = 512, NHq = 256, NM = 80;
constexpr int NC = 1024, NC2 = 512, NT = 800;
constexpr int NBLK = 256, NTHR = 512;

constexpr size_t OFF_KEYT  = 0;                                   // 32*256*512 f32
constexpr size_t OFF_WKT   = OFF_KEYT + (size_t)NB * NS * NC2;    // 512*512 f32
constexpr size_t OFF_PU    = OFF_WKT + (size_t)NI * NC2;          // 2*32*512 f32 [b][i]
constexpr size_t OFF_H     = OFF_PU + (size_t)2 * NB * NI;        // 2*1024*32 f32 [c][b]
constexpr size_t OFF_H16   = OFF_H + (size_t)2 * NC * NB;         // 2*32*1024 u16 [b][c]
constexpr size_t OFF_E     = OFF_H16 + (size_t)NB * NC;           // 2*32*256 f32
constexpr size_t OFF_W     = OFF_E + (size_t)2 * NB * NS;         // 2*32*256 f32
constexpr size_t OFF_SE    = OFF_W + (size_t)2 * NB * NS;         // 64
constexpr size_t OFF_SW    = OFF_SE + 64;                         // 64
constexpr size_t OFF_TPART = OFF_SW + 64;                         // [b][blk] 32*256
constexpr size_t OFF_TRED  = OFF_TPART + (size_t)NB * NBLK;       // 32 (unused)
constexpr size_t OFF_QBUF  = OFF_TRED + 32;                       // 32*512
constexpr size_t OFF_BAR   = OFF_QBUF + (size_t)NB * NC2;         // 8192 uints
constexpr size_t OFF_Q16   = OFF_BAR + 8192;                      // 800*32*256 u16
constexpr size_t OFF_F16   = OFF_Q16 + (size_t)NT * NB * NHq / 2; // 800*32*128 u16
constexpr size_t OFF_WQ16  = OFF_F16 + (size_t)NT * NB * 128 / 2; // 512*1024 u16
constexpr size_t OFF_ENC16 = OFF_WQ16 + (size_t)NC2 * NC / 2;     // 32*256*512 u16
constexpr size_t WS_FLOATS = OFF_ENC16 + (size_t)NB * NS * NI / 2;
}
using namespace cfg;

typedef __attribute__((ext_vector_type(8))) short short8;
typedef __attribute__((ext_vector_type(4))) float f32x4;
typedef __attribute__((ext_vector_type(4))) unsigned u32x4;

#define MF(a, b, c) __builtin_amdgcn_mfma_f32_16x16x32_bf16((a), (b), (c), 0, 0, 0)
// coherent (agent-scope, L1/L2-bypassing) 16B load, NO wait — group + vw*()
#define LDSC(d, p) asm volatile("global_load_dwordx4 %0, %1, off sc0 sc1" : "=v"(d) : "v"(p))

__device__ __forceinline__ float ld_cg(const float* p) {
  return __hip_atomic_load(p, __ATOMIC_RELAXED, __HIP_MEMORY_SCOPE_AGENT);
}
__device__ __forceinline__ void st_cg(float* p, float v) {
  __hip_atomic_store(p, v, __ATOMIC_RELAXED, __HIP_MEMORY_SCOPE_AGENT);
}
__device__ __forceinline__ void st_cg_u16(unsigned short* p, unsigned short v) {
  asm volatile("global_store_short %0, %1, off sc0 sc1" :: "v"(p), "v"((unsigned)v) : "memory");
}

__device__ __forceinline__ void vw7(short8& a0, short8& a1, short8& a2, short8& a3,
                                    short8& a4, short8& a5, short8& a6) {
  asm volatile("s_waitcnt vmcnt(0)"
               : "+v"(a0), "+v"(a1), "+v"(a2), "+v"(a3), "+v"(a4), "+v"(a5), "+v"(a6));
}
__device__ __forceinline__ void vw8(short8& a0, short8& a1, short8& a2, short8& a3,
                                    short8& a4, short8& a5, short8& a6, short8& a7) {
  asm volatile("s_waitcnt vmcnt(0)"
               : "+v"(a0), "+v"(a1), "+v"(a2), "+v"(a3), "+v"(a4), "+v"(a5), "+v"(a6), "+v"(a7));
}
__device__ __forceinline__ void vw10(short8& a0, short8& a1, short8& a2, short8& a3, short8& a4,
                                     short8& a5, short8& a6, short8& a7, short8& a8, short8& a9) {
  asm volatile("s_waitcnt vmcnt(0)"
               : "+v"(a0), "+v"(a1), "+v"(a2), "+v"(a3), "+v"(a4), "+v"(a5), "+v"(a6),
                 "+v"(a7), "+v"(a8), "+v"(a9));
}
__device__ __forceinline__ void vw15(short8& a0, short8& a1, short8& a2, short8& a3, short8& a4,
                                     short8& a5, short8& a6, short8& a7, short8& a8, short8& a9,
                                     short8& aa, short8& ab2, short8& ac, short8& ad, short8& ae) {
  asm volatile("s_waitcnt vmcnt(0)"
               : "+v"(a0), "+v"(a1), "+v"(a2), "+v"(a3), "+v"(a4), "+v"(a5), "+v"(a6),
                 "+v"(a7), "+v"(a8), "+v"(a9), "+v"(aa), "+v"(ab2), "+v"(ac), "+v"(ad), "+v"(ae));
}
__device__ __forceinline__ void vw16f(f32x4& a0, f32x4& a1, f32x4& a2, f32x4& a3, f32x4& a4,
                                      f32x4& a5, f32x4& a6, f32x4& a7, f32x4& b0, f32x4& b1,
                                      f32x4& b2, f32x4& b3, f32x4& b4, f32x4& b5, f32x4& b6,
                                      f32x4& b7) {
  asm volatile("s_waitcnt vmcnt(0)"
               : "+v"(a0), "+v"(a1), "+v"(a2), "+v"(a3), "+v"(a4), "+v"(a5), "+v"(a6), "+v"(a7),
                 "+v"(b0), "+v"(b1), "+v"(b2), "+v"(b3), "+v"(b4), "+v"(b5), "+v"(b6), "+v"(b7));
}

__device__ __forceinline__ float frcp(float x) {
#if __has_builtin(__builtin_amdgcn_rcpf)
  return __builtin_amdgcn_rcpf(x);
#else
  return 1.f / x;
#endif
}
__device__ __forceinline__ float fsig(float x) { return frcp(1.f + __expf(-x)); }
__device__ __forceinline__ float ftanh(float x) {
  const float e = __expf(2.f * x);
  return 1.f - 2.f * frcp(e + 1.f);
}
__device__ __forceinline__ short f2bf(float f) {  // RNE f32 -> bf16 bits
  unsigned u = __float_as_uint(f);
  u += 0x7FFFu + ((u >> 16) & 1u);
  return (short)(u >> 16);
}
__device__ __forceinline__ float bfu(unsigned short u) {
  return __uint_as_float(((unsigned)u) << 16);
}
__device__ __forceinline__ short8 cvt8(f32x4 lo, f32x4 hi) {
  short8 a;
  a[0] = f2bf(lo[0]); a[1] = f2bf(lo[1]); a[2] = f2bf(lo[2]); a[3] = f2bf(lo[3]);
  a[4] = f2bf(hi[0]); a[5] = f2bf(hi[1]); a[6] = f2bf(hi[2]); a[7] = f2bf(hi[3]);
  return a;
}

// ---------------------------------------------------------------------------
// FLAT one-hop barrier. BAR layout (uints): [0..256) packed arrival flags
// (16 lines); [512..544) packed q flags (2 lines).
// Every block writes its word; every block polls ALL flags directly
// (64 threads x dwordx4). Detection = write visibility + one poll iteration.
// Max phase skew is 1 (a block cannot pass barrier k+1 until all wrote k+1),
// so monotone >= compare is safe.
__device__ __forceinline__ void gbarrier(unsigned* fl, unsigned& ph) {
  ++ph;
  asm volatile("s_waitcnt vmcnt(0)" ::: "memory");  // drain sc1 stores + atomics
  __syncthreads();
  if (threadIdx.x == 0)
    __hip_atomic_store(&fl[blockIdx.x], ph, __ATOMIC_RELAXED, __HIP_MEMORY_SCOPE_AGENT);
  if (threadIdx.x < 64) {
    const unsigned* p = fl + threadIdx.x * 4;
    for (;;) {
      u32x4 v;
      asm volatile("global_load_dwordx4 %0, %1, off sc0 sc1\n\ts_waitcnt vmcnt(0)"
                   : "=v"(v) : "v"(p));
      if (v[0] >= ph && v[1] >= ph && v[2] >= ph && v[3] >= ph) break;
      __builtin_amdgcn_s_sleep(2);
    }
  }
  __syncthreads();
}

// Wcat element (kind: 0=r,1=z,2=n,3=tp; c: channel; k: 0..1919)
__device__ __forceinline__ float wcat_val(const float* __restrict__ w_ih,
                                          const float* __restrict__ w_hh,
                                          const float* __restrict__ w_t1,
                                          int kind, int c, int k) {
  if (kind < 3) {
    const int gr = kind * NC + c;
    if (k < 768) return w_ih[(size_t)gr * 768 + k];
    if (k < 1792) return w_hh[(size_t)gr * NC + (k - 768)];
    return 0.f;
  }
  if (k >= 256 && k < 768) return w_t1[(size_t)c * 1616 + (k - 256)];
  if (k >= 768 && k < 1792) return w_t1[(size_t)c * 1616 + 592 + (k - 768)];
  if (k >= 1792 && k < 1872) return w_t1[(size_t)c * 1616 + 512 + (k - 1792)];
  return 0.f;
}

// ---------------------------------------------------------------------------
__global__ void k_init(const float* __restrict__ enc, const float* __restrict__ queries,
                       const float* __restrict__ outputs, const float* __restrict__ w_k,
                       const float* __restrict__ w_q, float* __restrict__ ws) {
  const size_t t0 = (size_t)blockIdx.x * blockDim.x + threadIdx.x;
  const size_t gs = (size_t)gridDim.x * blockDim.x;
  for (size_t x = t0; x < (size_t)NI * NC2; x += gs) {
    const int i = (int)(x / NC2), c2 = (int)(x % NC2);
    ws[OFF_WKT + x] = w_k[(size_t)c2 * NI + i];
  }
  // PU parity1 = enc[b,0,:]  (alpha_init one-hot at s=0, SW=1); parity0 = 0
  for (size_t x = t0; x < (size_t)NB * NI; x += gs) {
    const int b = (int)(x / NI), i = (int)(x % NI);
    ws[OFF_PU + x] = 0.f;
    ws[OFF_PU + (size_t)NB * NI + b * NI + i] = enc[(size_t)b * NS * NI + i];
  }
  for (size_t x = t0; x < (size_t)2 * NC * NB; x += gs) ws[OFF_H + x] = 0.f;
  for (size_t x = t0; x < (size_t)NB * NC; x += gs) ws[OFF_H16 + x] = 0.f;  // 2 u16 parities
  // e parity1 = 1 (SE=256); w parity1 = one-hot (SW=1)
  for (size_t x = t0; x < (size_t)NB * NS; x += gs) {
    ws[OFF_E + x] = 0.f;
    ws[OFF_E + (size_t)NB * NS + x] = 1.f;
    ws[OFF_W + x] = 0.f;
    ws[OFF_W + (size_t)NB * NS + x] = ((x & (NS - 1)) == 0) ? 1.f : 0.f;
  }
  for (size_t x = t0; x < (size_t)NB; x += gs) {
    ws[OFF_SE + x] = 0.f; ws[OFF_SE + NB + x] = (float)NS;
    ws[OFF_SW + x] = 0.f; ws[OFF_SW + NB + x] = 1.f;
    ws[OFF_TRED + x] = 0.f;
  }
  for (size_t x = t0; x < (size_t)NB * NBLK; x += gs) ws[OFF_TPART + x] = 0.f;
  unsigned* bar = (unsigned*)(ws + OFF_BAR);
  for (size_t x = t0; x < 8192; x += gs) bar[x] = 0u;
  unsigned short* Q16 = (unsigned short*)(ws + OFF_Q16);
  for (size_t x = t0; x < (size_t)NT * NB * NHq; x += gs) {
    const int k = (int)(x & (NHq - 1));
    const int b = (int)((x >> 8) & (NB - 1));
    const int t = (int)(x >> 13);
    Q16[x] = (unsigned short)f2bf(queries[((size_t)b * NT + t) * NHq + k]);
  }
  unsigned short* F16 = (unsigned short*)(ws + OFF_F16);
  for (size_t x = t0; x < (size_t)NT * NB * 128; x += gs) {
    const int k = (int)(x & 127);
    const int b = (int)((x >> 7) & (NB - 1));
    const int t = (int)(x >> 12);
    F16[x] = (k < NM) ? (unsigned short)f2bf(outputs[((size_t)b * NT + t) * NM + k]) : 0;
  }
  unsigned short* WQ16 = (unsigned short*)(ws + OFF_WQ16);
  for (size_t x = t0; x < (size_t)NC2 * NC; x += gs)
    WQ16[x] = (unsigned short)f2bf(w_q[x]);
  unsigned short* ENC16 = (unsigned short*)(ws + OFF_ENC16);
  for (size_t x = t0; x < (size_t)NB * NS * NI; x += gs)
    ENC16[x] = (unsigned short)f2bf(enc[x]);
}

// ---------------------------------------------------------------------------
// keyT[b][s][c2] = enc[b,s,:] @ w_k^T + b_k
__global__ __launch_bounds__(NTHR) void k_key(const float* __restrict__ enc,
                                              const float* __restrict__ b_k,
                                              float* __restrict__ ws) {
  __shared__ float encl[4 * NI];
  const int bid = blockIdx.x, tid = threadIdx.x;
  const int b = bid >> 3, s0 = (bid & 7) * 32;
  const float* wkT = ws + OFF_WKT;
  float* keyT = ws + OFF_KEYT;
  const float bk = b_k[tid];
  for (int q = 0; q < 8; ++q) {
    const int sb = s0 + q * 4;
    for (int x = tid; x < 4 * NI; x += NTHR) {
      const int ss = x >> 9, i = x & (NI - 1);
      encl[x] = enc[((size_t)(b * NS + sb + ss)) * NI + i];
    }
    __syncthreads();
    float a0 = bk, a1 = bk, a2 = bk, a3 = bk;
    for (int i = 0; i < NI; ++i) {
      const float wv = wkT[(size_t)i * NC2 + tid];
      a0 += wv * encl[i];           a1 += wv * encl[NI + i];
      a2 += wv * encl[2 * NI + i];  a3 += wv * encl[3 * NI + i];
    }
    keyT[((size_t)(b * NS + sb + 0)) * NC2 + tid] = a0;
    keyT[((size_t)(b * NS + sb + 1)) * NC2 + tid] = a1;
    keyT[((size_t)(b * NS + sb + 2)) * NC2 + tid] = a2;
    keyT[((size_t)(b * NS + sb + 3)) * NC2 + tid] = a3;
    __syncthreads();
  }
}

// ---------------------------------------------------------------------------
__global__ __launch_bounds__(NTHR, 2) void k_main(
    const float* __restrict__ enc, const float* __restrict__ mask,
    const float* __restrict__ w_ih, const float* __restrict__ w_hh,
    const float* __restrict__ b_ih, const float* __restrict__ b_hh,
    const float* __restrict__ w_loc1, const float* __restrict__ w_loc2,
    const float* __restrict__ w_agg, const float* __restrict__ w_t1,
    const float* __restrict__ b_t1, const float* __restrict__ w_t2,
    float* ws, float* __restrict__ out) {
  const int bid = blockIdx.x, tid = threadIdx.x;
  float* const keyT = ws + OFF_KEYT;
  float* const PU = ws + OFF_PU;
  float* const HB = ws + OFF_H;
  unsigned short* const HB16 = (unsigned short*)(ws + OFF_H16);
  float* const EB = ws + OFF_E;
  float* const WBUF = ws + OFF_W;
  float* const SEB = ws + OFF_SE;
  float* const SWB = ws + OFF_SW;
  float* const TPART = ws + OFF_TPART;
  float* const QBUF = ws + OFF_QBUF;
  unsigned* const barfl = (unsigned*)(ws + OFF_BAR);   // packed arrival flags
  unsigned* const qfl = barfl + 512;                   // packed q flags (32 u32)
  const unsigned short* const Q16 = (const unsigned short*)(ws + OFF_Q16);
  const unsigned short* const F16 = (const unsigned short*)(ws + OFF_F16);
  const unsigned short* const WQ16 = (const unsigned short*)(ws + OFF_WQ16);
  const unsigned short* const ENC16 = (const unsigned short*)(ws + OFF_ENC16);

  __shared__ float Cred[2 * 5 * 4 * 64];           // MFMA cross-wave reduce
  __shared__ float gout2[5 * 4 * 32];              // r,z,nx,nh,tp per (c4,b)
  __shared__ float swinv_l[32];
  __shared__ float tredl[128];
  __shared__ float redT[256];                      // TPART row partials
  __shared__ float alignl[72];                     // raw e window; [62..71] = 0
  __shared__ float wl2[34];
  __shared__ float qbl[520];                       // staged q for this block's b
  __shared__ float Epart[32 * 9];
  __shared__ float wstash[32];
  __shared__ float scal[4];

  const int lane = tid & 63, wv = tid >> 6;
  const int m2 = wv >> 2, k4 = wv & 3;        // PA roles
  const int kg = lane >> 4;                   // A/B fragment k-group
  const int ab = m2 * 16 + (lane & 15);       // A batch index for this lane
  const int cs = bid * 4;                     // block's 4 GRU channels
  const int pb_b = bid >> 3, pb_s0 = (bid & 7) * 32;  // PB roles
  const int col = lane & 15, quad = lane >> 4;        // PB MFMA roles
  unsigned ph = 0;

  // ---- one-time staging -------------------------------------------------
  // B-fragments of Wcat, persistent in VGPRs: wreg[si] for this wave's steps.
  short8 wreg[16];
  {
    const int n = lane & 15;
    const int kind = n >> 2, ch = cs + (n & 3);
#pragma unroll
    for (int si = 0; si < 16; ++si) {
      int s = (k4 == 0) ? (si < 8 ? si : (si < 15 ? 16 + si : -1))
            : (k4 == 1) ? 8 + si
            : (k4 == 2) ? (si < 15 ? 31 + si : -1)
                        : (si < 14 ? 46 + si : -1);
      short8 w = {0, 0, 0, 0, 0, 0, 0, 0};
      if (s >= 0) {
        const int k0 = s * 32 + kg * 8;
#pragma unroll
        for (int jj = 0; jj < 8; ++jj)
          w[jj] = f2bf(wcat_val(w_ih, w_hh, w_t1, kind, ch, k0 + jj));
      }
      wreg[si] = w;
    }
  }
  // PB persistent fragments: wave wv owns c2-tiles 4wv..4wv+3 (m), both sl
  // tiles (n). A = wcomb[k][c2] (bf16), key slice packed bf16, wag f32.
  short8 wcA[4];
  unsigned keylo[4][2], keyhi[4][2];
  f32x4 wagr[4];
#pragma unroll
  for (int t = 0; t < 4; ++t) {
    const int mt = 4 * wv + t;
    short8 wfr;
#pragma unroll
    for (int jj = 0; jj < 8; ++jj) {
      const int k = quad * 8 + jj;
      float s = 0.f;
      if (k < 31) {
        const int c2 = mt * 16 + col;
        for (int l = 0; l < 32; ++l) s += w_loc2[c2 * 32 + l] * w_loc1[l * 31 + k];
      }
      wfr[jj] = f2bf(s);
    }
    wcA[t] = wfr;
    const int c2r = mt * 16 + quad * 4;
#pragma unroll
    for (int r = 0; r < 4; ++r) wagr[t][r] = w_agg[c2r + r];
#pragma unroll
    for (int nt = 0; nt < 2; ++nt) {
      const float* kp = &keyT[((size_t)(pb_b * NS + pb_s0 + nt * 16 + col)) * NC2 + c2r];
      keylo[t][nt] = ((unsigned)(unsigned short)f2bf(kp[0])) |
                     (((unsigned)(unsigned short)f2bf(kp[1])) << 16);
      keyhi[t][nt] = ((unsigned)(unsigned short)f2bf(kp[2])) |
                     (((unsigned)(unsigned short)f2bf(kp[3])) << 16);
    }
  }
  if (tid >= 62 && tid < 72) alignl[tid] = 0.f;  // conv zero-pad tail (k=31 col)
  __syncthreads();

  for (int j = 0; j < NT; ++j) {
    const int p = j & 1;
    const float* pu_prev = PU + (size_t)(1 - p) * NB * NI;
    float* pu_cur = PU + (size_t)p * NB * NI;
    const float* h_prev = HB + (size_t)(1 - p) * NC * NB;
    float* h_cur = HB + (size_t)p * NC * NB;
    const unsigned short* hb16_prev = HB16 + (size_t)(1 - p) * NB * NC;
    unsigned short* hb16_cur = HB16 + (size_t)p * NB * NC;
    const float* e_prev = EB + (size_t)(1 - p) * NB * NS;
    float* e_cur = EB + (size_t)p * NB * NS;
    const float* w_prev = WBUF + (size_t)(1 - p) * NB * NS;
    float* w_cur = WBUF + (size_t)p * NB * NS;
    const float* se_prev = SEB + (size_t)(1 - p) * NB;
    float* se_cur = SEB + (size_t)p * NB;
    const float* sw_prev = SWB + (size_t)(1 - p) * NB;
    float* sw_cur = SWB + (size_t)p * NB;

    // ========================== Phase 1 (A + B staging) ==========================
    if (tid < 64) st_cg(&pu_cur[bid * 64 + tid], 0.f);
    if (bid == 0 && tid < NB) st_cg(&se_cur[tid], 0.f);
    if (bid == 1 && tid < NB) st_cg(&sw_cur[tid], 0.f);
    if (tid < NB) swinv_l[tid] = 1.f / ld_cg(&sw_prev[tid]);
    if (tid == 0) scal[0] = ld_cg(&se_prev[pb_b]);
    // stage e/w halos for THIS step's merged B (stable since prev step's end)
    if (tid < 62) {
      const int sp = pb_s0 + tid - 15;
      alignl[tid] = (sp >= 0 && sp < NS) ? ld_cg(&e_prev[pb_b * NS + sp]) : 0.f;
    }
    if (tid >= 64 && tid < 97) {
      const int i2 = tid - 64, sp = pb_s0 + i2 - 1;
      wl2[i2] = (sp >= 0 && sp < NS) ? ld_cg(&w_prev[pb_b * NS + sp]) : 0.f;
    }
    __syncthreads();

    if (j >= 1 && bid < NB && tid < NS)
      out[((size_t)bid * NT + (j - 1)) * NS + tid] = ld_cg(&w_prev[bid * NS + tid]) * swinv_l[bid];

    f32x4 accA = {0.f, 0.f, 0.f, 0.f}, accB = {0.f, 0.f, 0.f, 0.f};
    if (k4 == 0) {
      const unsigned short* qp = Q16 + ((size_t)j * NB + ab) * NHq + kg * 8;
      const unsigned short* hp = hb16_prev + (size_t)ab * NC + kg * 8;
      short8 h0, h1, h2, h3, h4, h5, h6;
      LDSC(h0, hp);        LDSC(h1, hp + 32);   LDSC(h2, hp + 64);  LDSC(h3, hp + 96);
      LDSC(h4, hp + 128);  LDSC(h5, hp + 160);  LDSC(h6, hp + 192);
      const short8 q0 = *(const short8*)(qp);
      const short8 q1 = *(const short8*)(qp + 32);
      const short8 q2 = *(const short8*)(qp + 64);
      const short8 q3 = *(const short8*)(qp + 96);
      const short8 q4 = *(const short8*)(qp + 128);
      const short8 q5 = *(const short8*)(qp + 160);
      const short8 q6 = *(const short8*)(qp + 192);
      const short8 q7 = *(const short8*)(qp + 224);
      vw7(h0, h1, h2, h3, h4, h5, h6);
      accA = MF(q0, wreg[0], accA); accA = MF(q1, wreg[1], accA);
      accA = MF(q2, wreg[2], accA); accA = MF(q3, wreg[3], accA);
      accA = MF(q4, wreg[4], accA); accA = MF(q5, wreg[5], accA);
      accA = MF(q6, wreg[6], accA); accA = MF(q7, wreg[7], accA);
      accB = MF(h0, wreg[8], accB);  accB = MF(h1, wreg[9], accB);
      accB = MF(h2, wreg[10], accB); accB = MF(h3, wreg[11], accB);
      accB = MF(h4, wreg[12], accB); accB = MF(h5, wreg[13], accB);
      accB = MF(h6, wreg[14], accB);
    } else if (k4 == 1) {
      const float* pp = pu_prev + (size_t)ab * NI + kg * 8;
#pragma unroll
      for (int rd = 0; rd < 2; ++rd) {
        const float* pb = pp + rd * 256;
        f32x4 a0, a1, a2, a3, a4, a5, a6, a7, b0, b1, b2, b3, b4, b5, b6, b7;
        LDSC(a0, pb);        LDSC(b0, pb + 4);
        LDSC(a1, pb + 32);   LDSC(b1, pb + 36);
        LDSC(a2, pb + 64);   LDSC(b2, pb + 68);
        LDSC(a3, pb + 96);   LDSC(b3, pb + 100);
        LDSC(a4, pb + 128);  LDSC(b4, pb + 132);
        LDSC(a5, pb + 160);  LDSC(b5, pb + 164);
        LDSC(a6, pb + 192);  LDSC(b6, pb + 196);
        LDSC(a7, pb + 224);  LDSC(b7, pb + 228);
        vw16f(a0, a1, a2, a3, a4, a5, a6, a7, b0, b1, b2, b3, b4, b5, b6, b7);
        const int w0 = rd * 8;
        accA = MF(cvt8(a0, b0), wreg[w0 + 0], accA);
        accA = MF(cvt8(a1, b1), wreg[w0 + 1], accA);
        accA = MF(cvt8(a2, b2), wreg[w0 + 2], accA);
        accA = MF(cvt8(a3, b3), wreg[w0 + 3], accA);
        accA = MF(cvt8(a4, b4), wreg[w0 + 4], accA);
        accA = MF(cvt8(a5, b5), wreg[w0 + 5], accA);
        accA = MF(cvt8(a6, b6), wreg[w0 + 6], accA);
        accA = MF(cvt8(a7, b7), wreg[w0 + 7], accA);
      }
    } else if (k4 == 2) {
      const unsigned short* hp = hb16_prev + (size_t)ab * NC + kg * 8 + 224;
      short8 h0, h1, h2, h3, h4, h5, h6, h7, h8, h9, ha, hb2, hc, hd, he;
      LDSC(h0, hp);        LDSC(h1, hp + 32);  LDSC(h2, hp + 64);  LDSC(h3, hp + 96);
      LDSC(h4, hp + 128);  LDSC(h5, hp + 160); LDSC(h6, hp + 192); LDSC(h7, hp + 224);
      LDSC(h8, hp + 256);  LDSC(h9, hp + 288); LDSC(ha, hp + 320); LDSC(hb2, hp + 352);
      LDSC(hc, hp + 384);  LDSC(hd, hp + 416); LDSC(he, hp + 448);
      vw15(h0, h1, h2, h3, h4, h5, h6, h7, h8, h9, ha, hb2, hc, hd, he);
      accA = MF(h0, wreg[0], accA);  accA = MF(h1, wreg[1], accA);
      accA = MF(h2, wreg[2], accA);  accA = MF(h3, wreg[3], accA);
      accA = MF(h4, wreg[4], accA);  accA = MF(h5, wreg[5], accA);
      accA = MF(h6, wreg[6], accA);  accA = MF(h7, wreg[7], accA);
      accA = MF(h8, wreg[8], accA);  accA = MF(h9, wreg[9], accA);
      accA = MF(ha, wreg[10], accA); accA = MF(hb2, wreg[11], accA);
      accA = MF(hc, wreg[12], accA); accA = MF(hd, wreg[13], accA);
      accA = MF(he, wreg[14], accA);
    } else {
      const unsigned short* hp = hb16_prev + (size_t)ab * NC + kg * 8 + 704;
      short8 h0, h1, h2, h3, h4, h5, h6, h7, h8, h9;
      LDSC(h0, hp);        LDSC(h1, hp + 32);  LDSC(h2, hp + 64);  LDSC(h3, hp + 96);
      LDSC(h4, hp + 128);  LDSC(h5, hp + 160); LDSC(h6, hp + 192); LDSC(h7, hp + 224);
      LDSC(h8, hp + 256);  LDSC(h9, hp + 288);
      short8 f0 = {0,0,0,0,0,0,0,0}, f1 = f0, f2 = f0, f3 = f0;
      if (j > 0) {
        const unsigned short* fp = F16 + ((size_t)(j - 1) * NB + ab) * 128 + kg * 8;
        f0 = *(const short8*)(fp);
        f1 = *(const short8*)(fp + 32);
        f2 = *(const short8*)(fp + 64);
        f3 = *(const short8*)(fp + 96);
      }
      vw10(h0, h1, h2, h3, h4, h5, h6, h7, h8, h9);
      accA = MF(h0, wreg[0], accA); accA = MF(h1, wreg[1], accA);
      accA = MF(h2, wreg[2], accA); accA = MF(h3, wreg[3], accA);
      accA = MF(h4, wreg[4], accA); accA = MF(h5, wreg[5], accA);
      accA = MF(h6, wreg[6], accA); accA = MF(h7, wreg[7], accA);
      accA = MF(h8, wreg[8], accA); accA = MF(h9, wreg[9], accA);
      accA = MF(f0, wreg[10], accA); accA = MF(f1, wreg[11], accA);
      accA = MF(f2, wreg[12], accA); accA = MF(f3, wreg[13], accA);
    }
    // Cred[m2][sg][r][lane]: sg 0=w0.A(q) 1=w0.B(h-part) 2=w1.A(prev) 3=w2.A 4=w3.A
    {
      auto cidx = [](int m, int sg, int r, int l) { return ((m * 5 + sg) * 4 + r) * 64 + l; };
      if (k4 == 0) {
#pragma unroll
        for (int r = 0; r < 4; ++r) {
          Cred[cidx(m2, 0, r, lane)] = accA[r];
          Cred[cidx(m2, 1, r, lane)] = accB[r];
        }
      } else {
        const int sg = 1 + k4;
#pragma unroll
        for (int r = 0; r < 4; ++r) Cred[cidx(m2, sg, r, lane)] = accA[r];
      }
    }
    __syncthreads();
    {  // combine: gate = s0 + swinv*s1 + s2  (n-gate keeps x/h split)
      const int n = tid & 15, b = tid >> 4;
      const int m2r = b >> 4, bm = b & 15, l = (bm >> 2) * 16 + n, r = bm & 3;
      auto cidx = [](int m, int sg, int rr, int ll) { return ((m * 5 + sg) * 4 + rr) * 64 + ll; };
      const float s0 = Cred[cidx(m2r, 0, r, l)];
      const float sB = Cred[cidx(m2r, 1, r, l)];
      const float s1 = Cred[cidx(m2r, 2, r, l)];
      const float s2 = sB + Cred[cidx(m2r, 3, r, l)] + Cred[cidx(m2r, 4, r, l)];
      const float swv = swinv_l[b];
      const int kind = n >> 2, c4o = n & 3;
      if (kind == 2) {
        gout2[2 * 128 + c4o * 32 + b] = s0 + swv * s1;
        gout2[3 * 128 + c4o * 32 + b] = s2;
      } else {
        const int slot = (kind == 3) ? 4 : kind;
        gout2[slot * 128 + c4o * 32 + b] = s0 + swv * s1 + s2;
      }
    }
    __syncthreads();
    if (tid < 128) {  // GRU update, 4 channels x 32 batches
      const int c4o = tid >> 5, b = tid & 31, c = cs + c4o;
      const float xr = gout2[0 * 128 + c4o * 32 + b] + b_ih[c] + b_hh[c];
      const float xz = gout2[1 * 128 + c4o * 32 + b] + b_ih[NC + c] + b_hh[NC + c];
      const float xn = gout2[2 * 128 + c4o * 32 + b] + b_ih[2 * NC + c];
      const float hn = gout2[3 * 128 + c4o * 32 + b] + b_hh[2 * NC + c];
      const float tp = gout2[4 * 128 + c4o * 32 + b];
      const float r = fsig(xr), z = fsig(xz);
      const float nn = ftanh(xn + r * hn);
      const float hnew = (1.f - z) * nn + z * h_prev[c * 32 + b];
      h_cur[c * 32 + b] = hnew;
      st_cg_u16(&hb16_cur[(size_t)b * NC + c], (unsigned short)f2bf(hnew));
      tredl[c4o * 32 + b] = w_t2[c] * ftanh(tp + b_t1[c]);
    }
    __syncthreads();
    if (tid < NB)  // TPART transposed: [b][bid] — contiguous row per batch
      st_cg(&TPART[(size_t)tid * NBLK + bid],
            tredl[tid] + tredl[32 + tid] + tredl[64 + tid] + tredl[96 + tid]);
    gbarrier(barfl, ph);

    // ========================== Phase 2 (Q producers + merged B) ==========
    // early-issue TPART row read (overlaps producer work; waited at redT use)
    const float tpv = (tid < 256) ? ld_cg(&TPART[(size_t)pb_b * NBLK + tid]) : 0.f;

    if (bid < 32) {  // q = h_new @ w_q^T via MFMA; block owns 16 q-cols
      f32x4 qacc = {0.f, 0.f, 0.f, 0.f};
      const unsigned short* hb = hb16_cur + (size_t)ab * NC + kg * 8;
      short8 g0, g1, g2, g3, g4, g5, g6, g7;
      LDSC(g0, hb + (k4 * 8 + 0) * 32); LDSC(g1, hb + (k4 * 8 + 1) * 32);
      LDSC(g2, hb + (k4 * 8 + 2) * 32); LDSC(g3, hb + (k4 * 8 + 3) * 32);
      LDSC(g4, hb + (k4 * 8 + 4) * 32); LDSC(g5, hb + (k4 * 8 + 5) * 32);
      LDSC(g6, hb + (k4 * 8 + 6) * 32); LDSC(g7, hb + (k4 * 8 + 7) * 32);
      const int jq = bid * 16 + col;
      const unsigned short* wp = WQ16 + (size_t)jq * NC + k4 * 8 * 32 + kg * 8;
      vw8(g0, g1, g2, g3, g4, g5, g6, g7);
      qacc = MF(g0, *(const short8*)(wp), qacc);
      qacc = MF(g1, *(const short8*)(wp + 32), qacc);
      qacc = MF(g2, *(const short8*)(wp + 64), qacc);
      qacc = MF(g3, *(const short8*)(wp + 96), qacc);
      qacc = MF(g4, *(const short8*)(wp + 128), qacc);
      qacc = MF(g5, *(const short8*)(wp + 160), qacc);
      qacc = MF(g6, *(const short8*)(wp + 192), qacc);
      qacc = MF(g7, *(const short8*)(wp + 224), qacc);
#pragma unroll
      for (int r = 0; r < 4; ++r) Cred[((m2 * 4 + k4) * 4 + r) * 64 + lane] = qacc[r];
      __syncthreads();
      {
        const int col2 = tid & 15, b2 = tid >> 4;
        const int m2r = b2 >> 4, bm = b2 & 15, l = (bm >> 2) * 16 + col2, r = bm & 3;
        float s = 0.f;
#pragma unroll
        for (int kk = 0; kk < 4; ++kk) s += Cred[((m2r * 4 + kk) * 4 + r) * 64 + l];
        st_cg(&QBUF[(size_t)b2 * NC2 + bid * 16 + col2], s);
      }
      asm volatile("s_waitcnt vmcnt(0)" ::: "memory");  // drain own QBUF stores
      __syncthreads();                                  // all waves drained
      if (tid == 0)
        __hip_atomic_store(&qfl[bid], (unsigned)(j + 1),
                           __ATOMIC_RELAXED, __HIP_MEMORY_SCOPE_AGENT);
    }

    // ---- local trans reduce (TPART row) ----
    if (tid < 256) redT[tid] = tpv;
    __syncthreads();
    if (tid < 64) {
      float s = redT[tid] + redT[tid + 64] + redT[tid + 128] + redT[tid + 192];
#pragma unroll
      for (int off = 32; off > 0; off >>= 1) s += __shfl_xor(s, off);
      if (tid == 0) scal[2] = s;
    }
    // ---- conv precompute: D = wcomb·(e_prev/SE) + key (overlaps producers) --
    f32x4 bacc[2][4];
    {
      const float invSE = 1.f / scal[0];
#pragma unroll
      for (int nt = 0; nt < 2; ++nt) {
        const int base = nt * 16 + col + quad * 8;
        short8 bv;
#pragma unroll
        for (int jj = 0; jj < 8; ++jj) bv[jj] = f2bf(alignl[base + jj] * invSE);
#pragma unroll
        for (int t = 0; t < 4; ++t) {
          f32x4 acc;
          acc[0] = __uint_as_float(keylo[t][nt] << 16);
          acc[1] = __uint_as_float(keylo[t][nt] & 0xffff0000u);
          acc[2] = __uint_as_float(keyhi[t][nt] << 16);
          acc[3] = __uint_as_float(keyhi[t][nt] & 0xffff0000u);
          bacc[nt][t] = MF(wcA[t], bv, acc);
        }
      }
    }
    // ---- FLAT mini-barrier: poll the 32 packed q flags directly ----------
    if (tid < 8) {
      const unsigned tgt = (unsigned)(j + 1);
      const unsigned* p = qfl + tid * 4;
      for (;;) {
        u32x4 v;
        asm volatile("global_load_dwordx4 %0, %1, off sc0 sc1\n\ts_waitcnt vmcnt(0)"
                     : "=v"(v) : "v"(p));
        if (v[0] >= tgt && v[1] >= tgt && v[2] >= tgt && v[3] >= tgt) break;
        __builtin_amdgcn_s_sleep(2);
      }
    }
    __syncthreads();

    // ---- B residual ----
    {
      const int b = pb_b, s0v = pb_s0;
      qbl[tid] = ld_cg(&QBUF[(size_t)b * NC2 + tid]);  // stage q -> LDS
      __syncthreads();
      const float invSW = swinv_l[b];
      const float tr = (j == 0) ? 0.5f : fsig(scal[2]);
      // epilogue: tanh(conv+key+q)·wag, reduce over c2
#pragma unroll
      for (int nt = 0; nt < 2; ++nt) {
        float pe = 0.f;
#pragma unroll
        for (int t = 0; t < 4; ++t) {
          const int c2b = (4 * wv + t) * 16 + quad * 4;
          const f32x4 av = bacc[nt][t];
          pe += wagr[t][0] * ftanh(av[0] + qbl[c2b + 0]);
          pe += wagr[t][1] * ftanh(av[1] + qbl[c2b + 1]);
          pe += wagr[t][2] * ftanh(av[2] + qbl[c2b + 2]);
          pe += wagr[t][3] * ftanh(av[3] + qbl[c2b + 3]);
        }
        pe += __shfl_xor(pe, 16);
        pe += __shfl_xor(pe, 32);
        if (lane < 16) Epart[(nt * 16 + col) * 9 + wv] = pe;
      }
      __syncthreads();
      if (tid < 32) {  // finalize energies for this block's 32 s-positions
        const int sl = tid, s = s0v + sl;
        float Ev = 0.f;
#pragma unroll
        for (int w8 = 0; w8 < 8; ++w8) Ev += Epart[sl * 9 + w8];
        const float ev = (mask[b * NS + s] != 0.f) ? __expf(Ev) : 0.f;
        const float csv = ((1.f - tr) * wl2[sl + 1] + tr * wl2[sl]) * invSW + 1e-7f;
        const float wvv = csv * ev;
        st_cg(&e_cur[b * NS + s], ev);
        st_cg(&w_cur[b * NS + s], wvv);
        wstash[sl] = wvv;
        float se = ev, sw2 = wvv;
#pragma unroll
        for (int off = 16; off > 0; off >>= 1) {
          se += __shfl_down(se, off, 32);
          sw2 += __shfl_down(sw2, off, 32);
        }
        if (sl == 0) { atomicAdd(&se_cur[b], se); atomicAdd(&sw_cur[b], sw2); }
      }
      __syncthreads();
      {  // prevU[b][i] += sum_s w_s * enc16[b,s,i]  (bf16 enc, L2-resident)
        const unsigned short* ep = ENC16 + ((size_t)(b * NS + s0v)) * NI + tid;
        float acc = 0.f;
#pragma unroll 8
        for (int ss = 0; ss < 32; ++ss) acc += wstash[ss] * bfu(ep[(size_t)ss * NI]);
        atomicAdd(&pu_cur[(size_t)b * NI + tid], acc);
      }
    }
    gbarrier(barfl, ph);
  }

  // epilogue: alpha_{T-1} (parity 1 since 799 is odd)
  if (bid < NB && tid < NS) {
    const float invSW = 1.f / ld_cg(&SWB[NB + bid]);
    out[((size_t)bid * NT + (NT - 1)) * NS + tid] =
        ld_cg(&WBUF[(size_t)NB * NS + bid * NS + tid]) * invSW;
  }
}

// ---------------------------------------------------------------------------
extern "C" void kernel_launch(void* const* d_in, const int* in_sizes, int n_in,
                              void* d_out, int out_size, void* d_ws, size_t ws_size,
                              hipStream_t stream) {
  const float* enc     = (const float*)d_in[0];
  const float* queries = (const float*)d_in[1];
  const float* outputs = (const float*)d_in[2];
  const float* mask    = (const float*)d_in[3];
  const float* w_ih    = (const float*)d_in[4];
  const float* w_hh    = (const float*)d_in[5];
  const float* b_ih    = (const float*)d_in[6];
  const float* b_hh    = (const float*)d_in[7];
  const float* w_q     = (const float*)d_in[8];
  const float* w_loc1  = (const float*)d_in[9];
  const float* w_loc2  = (const float*)d_in[10];
  const float* w_k     = (const float*)d_in[11];
  const float* b_k     = (const float*)d_in[12];
  const float* w_agg   = (const float*)d_in[13];
  const float* w_t1    = (const float*)d_in[14];
  const float* b_t1    = (const float*)d_in[15];
  const float* w_t2    = (const float*)d_in[16];
  float* ws = (float*)d_ws;
  float* out = (float*)d_out;
  (void)in_sizes; (void)n_in; (void)out_size; (void)ws_size;

  k_init<<<dim3(1024), dim3(256), 0, stream>>>(enc, queries, outputs, w_k, w_q, ws);
  k_key<<<dim3(NBLK), dim3(NTHR), 0, stream>>>(enc, b_k, ws);
  k_main<<<dim3(NBLK), dim3(NTHR), 0, stream>>>(enc, mask, w_ih, w_hh, b_ih, b_hh,
                                                w_loc1, w_loc2, w_agg, w_t1,
                                                b_t1, w_t2, ws, out);
}

// Round 8
// 19289.323 us; speedup vs baseline: 1.2599x; 1.2599x over previous
//
#include <hip/hip_runtime.h>
#include <cstdint>
#include <cstddef>

// ============================================================================
// Aligner (forward attention + GRU), persistent-kernel, MFMA-bf16 edition.
// Round 14: producer/consumer DATAFLOW replaces two of three rendezvous.
//   - Phase-1 grid barrier DELETED. Each block drains h/TPART stores and sets
//     a packed per-block flag; only the 32 q-PRODUCER blocks poll the 256
//     flags (2K pollers on 16 lines -- 8x below R13's failure scale). The
//     other 224 blocks proceed straight to conv precompute + q polling.
//   - q mini-barrier + QBUF read DELETED. Producers publish q as tagged 16B
//     chunks ({f0,f1,f2,step-tag} per dwordx4 store -- single-instruction 16B
//     writes are atomic at the coherence point). Consumers poll the data
//     lines directly (193 thr/block, lines spread over 32 batches): detection
//     and payload arrive in the same load.
//   - TRED rides with q: producer bid reduces TPART row bid post-poll and
//     publishes one tagged chunk; the per-block TPART read/reduce is deleted.
//   - End-of-step barrier stays the PROVEN two-hop flag barrier (R10/R11) --
//     flat barriers regressed twice (R7, R13).
// Keeps R10/R11 wins: transposed TPART, ENC16 pu, merged Phase 2.
// ============================================================================

namespace cfg {
constexpr int NB = 32, NS = 256, NI = 512, NHq = 256, NM = 80;
constexpr int NC = 1024, NC2 = 512, NT = 800;
constexpr int NBLK = 256, NTHR = 512;

constexpr size_t OFF_KEYT  = 0;                                   // 32*256*512 f32
constexpr size_t OFF_WKT   = OFF_KEYT + (size_t)NB * NS * NC2;    // 512*512 f32
constexpr size_t OFF_PU    = OFF_WKT + (size_t)NI * NC2;          // 2*32*512 f32 [b][i]
constexpr size_t OFF_H     = OFF_PU + (size_t)2 * NB * NI;        // 2*1024*32 f32 [c][b]
constexpr size_t OFF_H16   = OFF_H + (size_t)2 * NC * NB;         // 2*32*1024 u16 [b][c]
constexpr size_t OFF_E     = OFF_H16 + (size_t)NB * NC;           // 2*32*256 f32
constexpr size_t OFF_W     = OFF_E + (size_t)2 * NB * NS;         // 2*32*256 f32
constexpr size_t OFF_SE    = OFF_W + (size_t)2 * NB * NS;         // 64
constexpr size_t OFF_SW    = OFF_SE + 64;                         // 64
constexpr size_t OFF_TPART = OFF_SW + 64;                         // [b][blk] 32*256
constexpr size_t OFF_TRED  = OFF_TPART + (size_t)NB * NBLK;       // 32 (unused)
constexpr size_t OFF_QBUF  = OFF_TRED + 32;                       // 32*512 (unused)
constexpr size_t OFF_BAR   = OFF_QBUF + (size_t)NB * NC2;         // 8192 uints
constexpr size_t OFF_Q16   = OFF_BAR + 8192;                      // 800*32*256 u16
constexpr size_t OFF_F16   = OFF_Q16 + (size_t)NT * NB * NHq / 2; // 800*32*128 u16
constexpr size_t OFF_WQ16  = OFF_F16 + (size_t)NT * NB * 128 / 2; // 512*1024 u16
constexpr size_t OFF_ENC16 = OFF_WQ16 + (size_t)NC2 * NC / 2;     // 32*256*512 u16
constexpr size_t OFF_QT    = OFF_ENC16 + (size_t)NB * NS * NI / 2;// 32*32*6 chunks u32x4
constexpr size_t OFF_TRC   = OFF_QT + 24576;                      // 32 chunks u32x4
constexpr size_t WS_FLOATS = OFF_TRC + 128;
}
using namespace cfg;

typedef __attribute__((ext_vector_type(8))) short short8;
typedef __attribute__((ext_vector_type(4))) float f32x4;
typedef __attribute__((ext_vector_type(4))) unsigned u32x4;

#define MF(a, b, c) __builtin_amdgcn_mfma_f32_16x16x32_bf16((a), (b), (c), 0, 0, 0)
// coherent (agent-scope, L1/L2-bypassing) 16B load, NO wait — group + vw*()
#define LDSC(d, p) asm volatile("global_load_dwordx4 %0, %1, off sc0 sc1" : "=v"(d) : "v"(p))
// coherent 16B load + wait (for poll loops)
#define LDSC4W(d, p) asm volatile("global_load_dwordx4 %0, %1, off sc0 sc1\n\ts_waitcnt vmcnt(0)" \
                                  : "=v"(d) : "v"(p))
// coherent 16B store (tagged chunk publish)
#define STSC4(p, d) asm volatile("global_store_dwordx4 %0, %1, off sc0 sc1" :: "v"(p), "v"(d) : "memory")

__device__ __forceinline__ float ld_cg(const float* p) {
  return __hip_atomic_load(p, __ATOMIC_RELAXED, __HIP_MEMORY_SCOPE_AGENT);
}
__device__ __forceinline__ void st_cg(float* p, float v) {
  __hip_atomic_store(p, v, __ATOMIC_RELAXED, __HIP_MEMORY_SCOPE_AGENT);
}
__device__ __forceinline__ void st_cg_u16(unsigned short* p, unsigned short v) {
  asm volatile("global_store_short %0, %1, off sc0 sc1" :: "v"(p), "v"((unsigned)v) : "memory");
}

__device__ __forceinline__ void vw7(short8& a0, short8& a1, short8& a2, short8& a3,
                                    short8& a4, short8& a5, short8& a6) {
  asm volatile("s_waitcnt vmcnt(0)"
               : "+v"(a0), "+v"(a1), "+v"(a2), "+v"(a3), "+v"(a4), "+v"(a5), "+v"(a6));
}
__device__ __forceinline__ void vw8(short8& a0, short8& a1, short8& a2, short8& a3,
                                    short8& a4, short8& a5, short8& a6, short8& a7) {
  asm volatile("s_waitcnt vmcnt(0)"
               : "+v"(a0), "+v"(a1), "+v"(a2), "+v"(a3), "+v"(a4), "+v"(a5), "+v"(a6), "+v"(a7));
}
__device__ __forceinline__ void vw10(short8& a0, short8& a1, short8& a2, short8& a3, short8& a4,
                                     short8& a5, short8& a6, short8& a7, short8& a8, short8& a9) {
  asm volatile("s_waitcnt vmcnt(0)"
               : "+v"(a0), "+v"(a1), "+v"(a2), "+v"(a3), "+v"(a4), "+v"(a5), "+v"(a6),
                 "+v"(a7), "+v"(a8), "+v"(a9));
}
__device__ __forceinline__ void vw15(short8& a0, short8& a1, short8& a2, short8& a3, short8& a4,
                                     short8& a5, short8& a6, short8& a7, short8& a8, short8& a9,
                                     short8& aa, short8& ab2, short8& ac, short8& ad, short8& ae) {
  asm volatile("s_waitcnt vmcnt(0)"
               : "+v"(a0), "+v"(a1), "+v"(a2), "+v"(a3), "+v"(a4), "+v"(a5), "+v"(a6),
                 "+v"(a7), "+v"(a8), "+v"(a9), "+v"(aa), "+v"(ab2), "+v"(ac), "+v"(ad), "+v"(ae));
}
__device__ __forceinline__ void vw16f(f32x4& a0, f32x4& a1, f32x4& a2, f32x4& a3, f32x4& a4,
                                      f32x4& a5, f32x4& a6, f32x4& a7, f32x4& b0, f32x4& b1,
                                      f32x4& b2, f32x4& b3, f32x4& b4, f32x4& b5, f32x4& b6,
                                      f32x4& b7) {
  asm volatile("s_waitcnt vmcnt(0)"
               : "+v"(a0), "+v"(a1), "+v"(a2), "+v"(a3), "+v"(a4), "+v"(a5), "+v"(a6), "+v"(a7),
                 "+v"(b0), "+v"(b1), "+v"(b2), "+v"(b3), "+v"(b4), "+v"(b5), "+v"(b6), "+v"(b7));
}

__device__ __forceinline__ float frcp(float x) {
#if __has_builtin(__builtin_amdgcn_rcpf)
  return __builtin_amdgcn_rcpf(x);
#else
  return 1.f / x;
#endif
}
__device__ __forceinline__ float fsig(float x) { return frcp(1.f + __expf(-x)); }
__device__ __forceinline__ float ftanh(float x) {
  const float e = __expf(2.f * x);
  return 1.f - 2.f * frcp(e + 1.f);
}
__device__ __forceinline__ short f2bf(float f) {  // RNE f32 -> bf16 bits
  unsigned u = __float_as_uint(f);
  u += 0x7FFFu + ((u >> 16) & 1u);
  return (short)(u >> 16);
}
__device__ __forceinline__ float bfu(unsigned short u) {
  return __uint_as_float(((unsigned)u) << 16);
}
__device__ __forceinline__ short8 cvt8(f32x4 lo, f32x4 hi) {
  short8 a;
  a[0] = f2bf(lo[0]); a[1] = f2bf(lo[1]); a[2] = f2bf(lo[2]); a[3] = f2bf(lo[3]);
  a[4] = f2bf(hi[0]); a[5] = f2bf(hi[1]); a[6] = f2bf(hi[2]); a[7] = f2bf(hi[3]);
  return a;
}

// Two-hop flag barrier (R10/R11 proven form; flat variants regressed twice).
// BAR layout (uints): [0..16) legacy root, [16..4112) flags x16-stride,
// [4352..4864) rootrep[32]x16, [5120..5376) packed h-ready flags (256 u32).
__device__ __forceinline__ void gbarrier(unsigned* root, unsigned* flags, unsigned& ph) {
  ++ph;
  asm volatile("s_waitcnt vmcnt(0)" ::: "memory");  // drain sc1 stores + atomics
  __syncthreads();
  unsigned* rootrep = root + 4352;
  if (blockIdx.x == 0) {
    const int t = threadIdx.x;
    if (t > 0 && t < 256) {
      while (__hip_atomic_load(&flags[t * 16], __ATOMIC_RELAXED, __HIP_MEMORY_SCOPE_AGENT) < ph)
        __builtin_amdgcn_s_sleep(1);
    }
    __syncthreads();
    if (t < 32)
      __hip_atomic_store(&rootrep[t * 16], ph, __ATOMIC_RELAXED, __HIP_MEMORY_SCOPE_AGENT);
  } else {
    if (threadIdx.x == 0) {
      __hip_atomic_store(&flags[blockIdx.x * 16], ph, __ATOMIC_RELAXED, __HIP_MEMORY_SCOPE_AGENT);
      while (__hip_atomic_load(&rootrep[(blockIdx.x & 31) * 16], __ATOMIC_RELAXED,
                               __HIP_MEMORY_SCOPE_AGENT) < ph)
        __builtin_amdgcn_s_sleep(1);
    }
  }
  __syncthreads();
}

// Wcat element (kind: 0=r,1=z,2=n,3=tp; c: channel; k: 0..1919)
__device__ __forceinline__ float wcat_val(const float* __restrict__ w_ih,
                                          const float* __restrict__ w_hh,
                                          const float* __restrict__ w_t1,
                                          int kind, int c, int k) {
  if (kind < 3) {
    const int gr = kind * NC + c;
    if (k < 768) return w_ih[(size_t)gr * 768 + k];
    if (k < 1792) return w_hh[(size_t)gr * NC + (k - 768)];
    return 0.f;
  }
  if (k >= 256 && k < 768) return w_t1[(size_t)c * 1616 + (k - 256)];
  if (k >= 768 && k < 1792) return w_t1[(size_t)c * 1616 + 592 + (k - 768)];
  if (k >= 1792 && k < 1872) return w_t1[(size_t)c * 1616 + 512 + (k - 1792)];
  return 0.f;
}

// ---------------------------------------------------------------------------
__global__ void k_init(const float* __restrict__ enc, const float* __restrict__ queries,
                       const float* __restrict__ outputs, const float* __restrict__ w_k,
                       const float* __restrict__ w_q, float* __restrict__ ws) {
  const size_t t0 = (size_t)blockIdx.x * blockDim.x + threadIdx.x;
  const size_t gs = (size_t)gridDim.x * blockDim.x;
  for (size_t x = t0; x < (size_t)NI * NC2; x += gs) {
    const int i = (int)(x / NC2), c2 = (int)(x % NC2);
    ws[OFF_WKT + x] = w_k[(size_t)c2 * NI + i];
  }
  // PU parity1 = enc[b,0,:]  (alpha_init one-hot at s=0, SW=1); parity0 = 0
  for (size_t x = t0; x < (size_t)NB * NI; x += gs) {
    const int b = (int)(x / NI), i = (int)(x % NI);
    ws[OFF_PU + x] = 0.f;
    ws[OFF_PU + (size_t)NB * NI + b * NI + i] = enc[(size_t)b * NS * NI + i];
  }
  for (size_t x = t0; x < (size_t)2 * NC * NB; x += gs) ws[OFF_H + x] = 0.f;
  for (size_t x = t0; x < (size_t)NB * NC; x += gs) ws[OFF_H16 + x] = 0.f;  // 2 u16 parities
  // e parity1 = 1 (SE=256); w parity1 = one-hot (SW=1)
  for (size_t x = t0; x < (size_t)NB * NS; x += gs) {
    ws[OFF_E + x] = 0.f;
    ws[OFF_E + (size_t)NB * NS + x] = 1.f;
    ws[OFF_W + x] = 0.f;
    ws[OFF_W + (size_t)NB * NS + x] = ((x & (NS - 1)) == 0) ? 1.f : 0.f;
  }
  for (size_t x = t0; x < (size_t)NB; x += gs) {
    ws[OFF_SE + x] = 0.f; ws[OFF_SE + NB + x] = (float)NS;
    ws[OFF_SW + x] = 0.f; ws[OFF_SW + NB + x] = 1.f;
    ws[OFF_TRED + x] = 0.f;
  }
  for (size_t x = t0; x < (size_t)NB * NBLK; x += gs) ws[OFF_TPART + x] = 0.f;
  unsigned* bar = (unsigned*)(ws + OFF_BAR);
  for (size_t x = t0; x < 8192; x += gs) bar[x] = 0u;
  unsigned* qt = (unsigned*)(ws + OFF_QT);
  for (size_t x = t0; x < 24576 + 128; x += gs) qt[x] = 0u;   // QT + TRC tags
  unsigned short* Q16 = (unsigned short*)(ws + OFF_Q16);
  for (size_t x = t0; x < (size_t)NT * NB * NHq; x += gs) {
    const int k = (int)(x & (NHq - 1));
    const int b = (int)((x >> 8) & (NB - 1));
    const int t = (int)(x >> 13);
    Q16[x] = (unsigned short)f2bf(queries[((size_t)b * NT + t) * NHq + k]);
  }
  unsigned short* F16 = (unsigned short*)(ws + OFF_F16);
  for (size_t x = t0; x < (size_t)NT * NB * 128; x += gs) {
    const int k = (int)(x & 127);
    const int b = (int)((x >> 7) & (NB - 1));
    const int t = (int)(x >> 12);
    F16[x] = (k < NM) ? (unsigned short)f2bf(outputs[((size_t)b * NT + t) * NM + k]) : 0;
  }
  unsigned short* WQ16 = (unsigned short*)(ws + OFF_WQ16);
  for (size_t x = t0; x < (size_t)NC2 * NC; x += gs)
    WQ16[x] = (unsigned short)f2bf(w_q[x]);
  unsigned short* ENC16 = (unsigned short*)(ws + OFF_ENC16);
  for (size_t x = t0; x < (size_t)NB * NS * NI; x += gs)
    ENC16[x] = (unsigned short)f2bf(enc[x]);
}

// ---------------------------------------------------------------------------
// keyT[b][s][c2] = enc[b,s,:] @ w_k^T + b_k
__global__ __launch_bounds__(NTHR) void k_key(const float* __restrict__ enc,
                                              const float* __restrict__ b_k,
                                              float* __restrict__ ws) {
  __shared__ float encl[4 * NI];
  const int bid = blockIdx.x, tid = threadIdx.x;
  const int b = bid >> 3, s0 = (bid & 7) * 32;
  const float* wkT = ws + OFF_WKT;
  float* keyT = ws + OFF_KEYT;
  const float bk = b_k[tid];
  for (int q = 0; q < 8; ++q) {
    const int sb = s0 + q * 4;
    for (int x = tid; x < 4 * NI; x += NTHR) {
      const int ss = x >> 9, i = x & (NI - 1);
      encl[x] = enc[((size_t)(b * NS + sb + ss)) * NI + i];
    }
    __syncthreads();
    float a0 = bk, a1 = bk, a2 = bk, a3 = bk;
    for (int i = 0; i < NI; ++i) {
      const float wv = wkT[(size_t)i * NC2 + tid];
      a0 += wv * encl[i];           a1 += wv * encl[NI + i];
      a2 += wv * encl[2 * NI + i];  a3 += wv * encl[3 * NI + i];
    }
    keyT[((size_t)(b * NS + sb + 0)) * NC2 + tid] = a0;
    keyT[((size_t)(b * NS + sb + 1)) * NC2 + tid] = a1;
    keyT[((size_t)(b * NS + sb + 2)) * NC2 + tid] = a2;
    keyT[((size_t)(b * NS + sb + 3)) * NC2 + tid] = a3;
    __syncthreads();
  }
}

// ---------------------------------------------------------------------------
__global__ __launch_bounds__(NTHR, 2) void k_main(
    const float* __restrict__ enc, const float* __restrict__ mask,
    const float* __restrict__ w_ih, const float* __restrict__ w_hh,
    const float* __restrict__ b_ih, const float* __restrict__ b_hh,
    const float* __restrict__ w_loc1, const float* __restrict__ w_loc2,
    const float* __restrict__ w_agg, const float* __restrict__ w_t1,
    const float* __restrict__ b_t1, const float* __restrict__ w_t2,
    float* ws, float* __restrict__ out) {
  const int bid = blockIdx.x, tid = threadIdx.x;
  float* const keyT = ws + OFF_KEYT;
  float* const PU = ws + OFF_PU;
  float* const HB = ws + OFF_H;
  unsigned short* const HB16 = (unsigned short*)(ws + OFF_H16);
  float* const EB = ws + OFF_E;
  float* const WBUF = ws + OFF_W;
  float* const SEB = ws + OFF_SE;
  float* const SWB = ws + OFF_SW;
  float* const TPART = ws + OFF_TPART;
  unsigned* const root = (unsigned*)(ws + OFF_BAR);
  unsigned* const flags = root + 16;
  unsigned* const hfl = root + 5120;                   // packed h-ready flags
  unsigned* const qt = (unsigned*)(ws + OFF_QT);       // tagged q chunks
  unsigned* const trc = (unsigned*)(ws + OFF_TRC);     // tagged TRED chunks
  const unsigned short* const Q16 = (const unsigned short*)(ws + OFF_Q16);
  const unsigned short* const F16 = (const unsigned short*)(ws + OFF_F16);
  const unsigned short* const WQ16 = (const unsigned short*)(ws + OFF_WQ16);
  const unsigned short* const ENC16 = (const unsigned short*)(ws + OFF_ENC16);

  __shared__ float Cred[2 * 5 * 4 * 64];           // MFMA cross-wave reduce
  __shared__ float gout2[5 * 4 * 32];              // r,z,nx,nh,tp per (c4,b)
  __shared__ float swinv_l[32];
  __shared__ float tredl[128];
  __shared__ float redT[256];                      // TPART row partials (producers)
  __shared__ float alignl[72];                     // raw e window; [62..71] = 0
  __shared__ float wl2[34];
  __shared__ float qbl[520];                       // q staging (dual use)
  __shared__ float Epart[32 * 9];
  __shared__ float wstash[32];
  __shared__ float scal[4];

  const int lane = tid & 63, wv = tid >> 6;
  const int m2 = wv >> 2, k4 = wv & 3;        // PA roles
  const int kg = lane >> 4;                   // A/B fragment k-group
  const int ab = m2 * 16 + (lane & 15);       // A batch index for this lane
  const int cs = bid * 4;                     // block's 4 GRU channels
  const int pb_b = bid >> 3, pb_s0 = (bid & 7) * 32;  // PB roles
  const int col = lane & 15, quad = lane >> 4;        // PB MFMA roles
  unsigned ph = 0;

  // ---- one-time staging -------------------------------------------------
  short8 wreg[16];
  {
    const int n = lane & 15;
    const int kind = n >> 2, ch = cs + (n & 3);
#pragma unroll
    for (int si = 0; si < 16; ++si) {
      int s = (k4 == 0) ? (si < 8 ? si : (si < 15 ? 16 + si : -1))
            : (k4 == 1) ? 8 + si
            : (k4 == 2) ? (si < 15 ? 31 + si : -1)
                        : (si < 14 ? 46 + si : -1);
      short8 w = {0, 0, 0, 0, 0, 0, 0, 0};
      if (s >= 0) {
        const int k0 = s * 32 + kg * 8;
#pragma unroll
        for (int jj = 0; jj < 8; ++jj)
          w[jj] = f2bf(wcat_val(w_ih, w_hh, w_t1, kind, ch, k0 + jj));
      }
      wreg[si] = w;
    }
  }
  short8 wcA[4];
  unsigned keylo[4][2], keyhi[4][2];
  f32x4 wagr[4];
#pragma unroll
  for (int t = 0; t < 4; ++t) {
    const int mt = 4 * wv + t;
    short8 wfr;
#pragma unroll
    for (int jj = 0; jj < 8; ++jj) {
      const int k = quad * 8 + jj;
      float s = 0.f;
      if (k < 31) {
        const int c2 = mt * 16 + col;
        for (int l = 0; l < 32; ++l) s += w_loc2[c2 * 32 + l] * w_loc1[l * 31 + k];
      }
      wfr[jj] = f2bf(s);
    }
    wcA[t] = wfr;
    const int c2r = mt * 16 + quad * 4;
#pragma unroll
    for (int r = 0; r < 4; ++r) wagr[t][r] = w_agg[c2r + r];
#pragma unroll
    for (int nt = 0; nt < 2; ++nt) {
      const float* kp = &keyT[((size_t)(pb_b * NS + pb_s0 + nt * 16 + col)) * NC2 + c2r];
      keylo[t][nt] = ((unsigned)(unsigned short)f2bf(kp[0])) |
                     (((unsigned)(unsigned short)f2bf(kp[1])) << 16);
      keyhi[t][nt] = ((unsigned)(unsigned short)f2bf(kp[2])) |
                     (((unsigned)(unsigned short)f2bf(kp[3])) << 16);
    }
  }
  if (tid >= 62 && tid < 72) alignl[tid] = 0.f;  // conv zero-pad tail (k=31 col)
  __syncthreads();

  for (int j = 0; j < NT; ++j) {
    const int p = j & 1;
    const float* pu_prev = PU + (size_t)(1 - p) * NB * NI;
    float* pu_cur = PU + (size_t)p * NB * NI;
    const float* h_prev = HB + (size_t)(1 - p) * NC * NB;
    float* h_cur = HB + (size_t)p * NC * NB;
    const unsigned short* hb16_prev = HB16 + (size_t)(1 - p) * NB * NC;
    unsigned short* hb16_cur = HB16 + (size_t)p * NB * NC;
    const float* e_prev = EB + (size_t)(1 - p) * NB * NS;
    float* e_cur = EB + (size_t)p * NB * NS;
    const float* w_prev = WBUF + (size_t)(1 - p) * NB * NS;
    float* w_cur = WBUF + (size_t)p * NB * NS;
    const float* se_prev = SEB + (size_t)(1 - p) * NB;
    float* se_cur = SEB + (size_t)p * NB;
    const float* sw_prev = SWB + (size_t)(1 - p) * NB;
    float* sw_cur = SWB + (size_t)p * NB;
    const unsigned tag = (unsigned)(j + 1);

    // ========================== Phase 1 (GRU + staging) ==================
    if (tid < 64) st_cg(&pu_cur[bid * 64 + tid], 0.f);
    if (bid == 0 && tid < NB) st_cg(&se_cur[tid], 0.f);
    if (bid == 1 && tid < NB) st_cg(&sw_cur[tid], 0.f);
    if (tid < NB) swinv_l[tid] = 1.f / ld_cg(&sw_prev[tid]);
    if (tid == 0) scal[0] = ld_cg(&se_prev[pb_b]);
    if (tid < 62) {
      const int sp = pb_s0 + tid - 15;
      alignl[tid] = (sp >= 0 && sp < NS) ? ld_cg(&e_prev[pb_b * NS + sp]) : 0.f;
    }
    if (tid >= 64 && tid < 97) {
      const int i2 = tid - 64, sp = pb_s0 + i2 - 1;
      wl2[i2] = (sp >= 0 && sp < NS) ? ld_cg(&w_prev[pb_b * NS + sp]) : 0.f;
    }
    __syncthreads();

    f32x4 accA = {0.f, 0.f, 0.f, 0.f}, accB = {0.f, 0.f, 0.f, 0.f};
    if (k4 == 0) {
      const unsigned short* qp = Q16 + ((size_t)j * NB + ab) * NHq + kg * 8;
      const unsigned short* hp = hb16_prev + (size_t)ab * NC + kg * 8;
      short8 h0, h1, h2, h3, h4, h5, h6;
      LDSC(h0, hp);        LDSC(h1, hp + 32);   LDSC(h2, hp + 64);  LDSC(h3, hp + 96);
      LDSC(h4, hp + 128);  LDSC(h5, hp + 160);  LDSC(h6, hp + 192);
      const short8 q0 = *(const short8*)(qp);
      const short8 q1 = *(const short8*)(qp + 32);
      const short8 q2 = *(const short8*)(qp + 64);
      const short8 q3 = *(const short8*)(qp + 96);
      const short8 q4 = *(const short8*)(qp + 128);
      const short8 q5 = *(const short8*)(qp + 160);
      const short8 q6 = *(const short8*)(qp + 192);
      const short8 q7 = *(const short8*)(qp + 224);
      vw7(h0, h1, h2, h3, h4, h5, h6);
      accA = MF(q0, wreg[0], accA); accA = MF(q1, wreg[1], accA);
      accA = MF(q2, wreg[2], accA); accA = MF(q3, wreg[3], accA);
      accA = MF(q4, wreg[4], accA); accA = MF(q5, wreg[5], accA);
      accA = MF(q6, wreg[6], accA); accA = MF(q7, wreg[7], accA);
      accB = MF(h0, wreg[8], accB);  accB = MF(h1, wreg[9], accB);
      accB = MF(h2, wreg[10], accB); accB = MF(h3, wreg[11], accB);
      accB = MF(h4, wreg[12], accB); accB = MF(h5, wreg[13], accB);
      accB = MF(h6, wreg[14], accB);
    } else if (k4 == 1) {
      const float* pp = pu_prev + (size_t)ab * NI + kg * 8;
#pragma unroll
      for (int rd = 0; rd < 2; ++rd) {
        const float* pb = pp + rd * 256;
        f32x4 a0, a1, a2, a3, a4, a5, a6, a7, b0, b1, b2, b3, b4, b5, b6, b7;
        LDSC(a0, pb);        LDSC(b0, pb + 4);
        LDSC(a1, pb + 32);   LDSC(b1, pb + 36);
        LDSC(a2, pb + 64);   LDSC(b2, pb + 68);
        LDSC(a3, pb + 96);   LDSC(b3, pb + 100);
        LDSC(a4, pb + 128);  LDSC(b4, pb + 132);
        LDSC(a5, pb + 160);  LDSC(b5, pb + 164);
        LDSC(a6, pb + 192);  LDSC(b6, pb + 196);
        LDSC(a7, pb + 224);  LDSC(b7, pb + 228);
        vw16f(a0, a1, a2, a3, a4, a5, a6, a7, b0, b1, b2, b3, b4, b5, b6, b7);
        const int w0 = rd * 8;
        accA = MF(cvt8(a0, b0), wreg[w0 + 0], accA);
        accA = MF(cvt8(a1, b1), wreg[w0 + 1], accA);
        accA = MF(cvt8(a2, b2), wreg[w0 + 2], accA);
        accA = MF(cvt8(a3, b3), wreg[w0 + 3], accA);
        accA = MF(cvt8(a4, b4), wreg[w0 + 4], accA);
        accA = MF(cvt8(a5, b5), wreg[w0 + 5], accA);
        accA = MF(cvt8(a6, b6), wreg[w0 + 6], accA);
        accA = MF(cvt8(a7, b7), wreg[w0 + 7], accA);
      }
    } else if (k4 == 2) {
      const unsigned short* hp = hb16_prev + (size_t)ab * NC + kg * 8 + 224;
      short8 h0, h1, h2, h3, h4, h5, h6, h7, h8, h9, ha, hb2, hc, hd, he;
      LDSC(h0, hp);        LDSC(h1, hp + 32);  LDSC(h2, hp + 64);  LDSC(h3, hp + 96);
      LDSC(h4, hp + 128);  LDSC(h5, hp + 160); LDSC(h6, hp + 192); LDSC(h7, hp + 224);
      LDSC(h8, hp + 256);  LDSC(h9, hp + 288); LDSC(ha, hp + 320); LDSC(hb2, hp + 352);
      LDSC(hc, hp + 384);  LDSC(hd, hp + 416); LDSC(he, hp + 448);
      vw15(h0, h1, h2, h3, h4, h5, h6, h7, h8, h9, ha, hb2, hc, hd, he);
      accA = MF(h0, wreg[0], accA);  accA = MF(h1, wreg[1], accA);
      accA = MF(h2, wreg[2], accA);  accA = MF(h3, wreg[3], accA);
      accA = MF(h4, wreg[4], accA);  accA = MF(h5, wreg[5], accA);
      accA = MF(h6, wreg[6], accA);  accA = MF(h7, wreg[7], accA);
      accA = MF(h8, wreg[8], accA);  accA = MF(h9, wreg[9], accA);
      accA = MF(ha, wreg[10], accA); accA = MF(hb2, wreg[11], accA);
      accA = MF(hc, wreg[12], accA); accA = MF(hd, wreg[13], accA);
      accA = MF(he, wreg[14], accA);
    } else {
      const unsigned short* hp = hb16_prev + (size_t)ab * NC + kg * 8 + 704;
      short8 h0, h1, h2, h3, h4, h5, h6, h7, h8, h9;
      LDSC(h0, hp);        LDSC(h1, hp + 32);  LDSC(h2, hp + 64);  LDSC(h3, hp + 96);
      LDSC(h4, hp + 128);  LDSC(h5, hp + 160); LDSC(h6, hp + 192); LDSC(h7, hp + 224);
      LDSC(h8, hp + 256);  LDSC(h9, hp + 288);
      short8 f0 = {0,0,0,0,0,0,0,0}, f1 = f0, f2 = f0, f3 = f0;
      if (j > 0) {
        const unsigned short* fp = F16 + ((size_t)(j - 1) * NB + ab) * 128 + kg * 8;
        f0 = *(const short8*)(fp);
        f1 = *(const short8*)(fp + 32);
        f2 = *(const short8*)(fp + 64);
        f3 = *(const short8*)(fp + 96);
      }
      vw10(h0, h1, h2, h3, h4, h5, h6, h7, h8, h9);
      accA = MF(h0, wreg[0], accA); accA = MF(h1, wreg[1], accA);
      accA = MF(h2, wreg[2], accA); accA = MF(h3, wreg[3], accA);
      accA = MF(h4, wreg[4], accA); accA = MF(h5, wreg[5], accA);
      accA = MF(h6, wreg[6], accA); accA = MF(h7, wreg[7], accA);
      accA = MF(h8, wreg[8], accA); accA = MF(h9, wreg[9], accA);
      accA = MF(f0, wreg[10], accA); accA = MF(f1, wreg[11], accA);
      accA = MF(f2, wreg[12], accA); accA = MF(f3, wreg[13], accA);
    }
    {
      auto cidx = [](int m, int sg, int r, int l) { return ((m * 5 + sg) * 4 + r) * 64 + l; };
      if (k4 == 0) {
#pragma unroll
        for (int r = 0; r < 4; ++r) {
          Cred[cidx(m2, 0, r, lane)] = accA[r];
          Cred[cidx(m2, 1, r, lane)] = accB[r];
        }
      } else {
        const int sg = 1 + k4;
#pragma unroll
        for (int r = 0; r < 4; ++r) Cred[cidx(m2, sg, r, lane)] = accA[r];
      }
    }
    __syncthreads();
    {
      const int n = tid & 15, b = tid >> 4;
      const int m2r = b >> 4, bm = b & 15, l = (bm >> 2) * 16 + n, r = bm & 3;
      auto cidx = [](int m, int sg, int rr, int ll) { return ((m * 5 + sg) * 4 + rr) * 64 + ll; };
      const float s0 = Cred[cidx(m2r, 0, r, l)];
      const float sB = Cred[cidx(m2r, 1, r, l)];
      const float s1 = Cred[cidx(m2r, 2, r, l)];
      const float s2 = sB + Cred[cidx(m2r, 3, r, l)] + Cred[cidx(m2r, 4, r, l)];
      const float swv = swinv_l[b];
      const int kind = n >> 2, c4o = n & 3;
      if (kind == 2) {
        gout2[2 * 128 + c4o * 32 + b] = s0 + swv * s1;
        gout2[3 * 128 + c4o * 32 + b] = s2;
      } else {
        const int slot = (kind == 3) ? 4 : kind;
        gout2[slot * 128 + c4o * 32 + b] = s0 + swv * s1 + s2;
      }
    }
    __syncthreads();
    if (tid < 128) {  // GRU update, 4 channels x 32 batches
      const int c4o = tid >> 5, b = tid & 31, c = cs + c4o;
      const float xr = gout2[0 * 128 + c4o * 32 + b] + b_ih[c] + b_hh[c];
      const float xz = gout2[1 * 128 + c4o * 32 + b] + b_ih[NC + c] + b_hh[NC + c];
      const float xn = gout2[2 * 128 + c4o * 32 + b] + b_ih[2 * NC + c];
      const float hn = gout2[3 * 128 + c4o * 32 + b] + b_hh[2 * NC + c];
      const float tp = gout2[4 * 128 + c4o * 32 + b];
      const float r = fsig(xr), z = fsig(xz);
      const float nn = ftanh(xn + r * hn);
      const float hnew = (1.f - z) * nn + z * h_prev[c * 32 + b];
      h_cur[c * 32 + b] = hnew;
      st_cg_u16(&hb16_cur[(size_t)b * NC + c], (unsigned short)f2bf(hnew));
      tredl[c4o * 32 + b] = w_t2[c] * ftanh(tp + b_t1[c]);
    }
    __syncthreads();
    if (tid < NB)  // TPART transposed: [b][bid]
      st_cg(&TPART[(size_t)tid * NBLK + bid],
            tredl[tid] + tredl[32 + tid] + tredl[64 + tid] + tredl[96 + tid]);
    // ---- h-ready flag: drain own stores, then announce. NO grid barrier. --
    asm volatile("s_waitcnt vmcnt(0)" ::: "memory");
    __syncthreads();
    if (tid == 0)
      __hip_atomic_store(&hfl[bid], tag, __ATOMIC_RELAXED, __HIP_MEMORY_SCOPE_AGENT);

    // ========================== Phase 2 (dataflow) =======================
    if (bid < 32) {  // q producer: block owns 16 q-cols for all 32 batches
      if (tid < 64) {  // poll all 256 h-flags (16 lines; 32 blocks only)
        const unsigned* pp = hfl + tid * 4;
        for (;;) {
          u32x4 v;
          LDSC4W(v, pp);
          if (v[0] >= tag && v[1] >= tag && v[2] >= tag && v[3] >= tag) break;
          __builtin_amdgcn_s_sleep(4);
        }
      }
      __syncthreads();
      if (tid < 256) redT[tid] = ld_cg(&TPART[(size_t)bid * NBLK + tid]);
      f32x4 qacc = {0.f, 0.f, 0.f, 0.f};
      const unsigned short* hb = hb16_cur + (size_t)ab * NC + kg * 8;
      short8 g0, g1, g2, g3, g4, g5, g6, g7;
      LDSC(g0, hb + (k4 * 8 + 0) * 32); LDSC(g1, hb + (k4 * 8 + 1) * 32);
      LDSC(g2, hb + (k4 * 8 + 2) * 32); LDSC(g3, hb + (k4 * 8 + 3) * 32);
      LDSC(g4, hb + (k4 * 8 + 4) * 32); LDSC(g5, hb + (k4 * 8 + 5) * 32);
      LDSC(g6, hb + (k4 * 8 + 6) * 32); LDSC(g7, hb + (k4 * 8 + 7) * 32);
      const int jq = bid * 16 + col;
      const unsigned short* wp = WQ16 + (size_t)jq * NC + k4 * 8 * 32 + kg * 8;
      vw8(g0, g1, g2, g3, g4, g5, g6, g7);
      qacc = MF(g0, *(const short8*)(wp), qacc);
      qacc = MF(g1, *(const short8*)(wp + 32), qacc);
      qacc = MF(g2, *(const short8*)(wp + 64), qacc);
      qacc = MF(g3, *(const short8*)(wp + 96), qacc);
      qacc = MF(g4, *(const short8*)(wp + 128), qacc);
      qacc = MF(g5, *(const short8*)(wp + 160), qacc);
      qacc = MF(g6, *(const short8*)(wp + 192), qacc);
      qacc = MF(g7, *(const short8*)(wp + 224), qacc);
#pragma unroll
      for (int r = 0; r < 4; ++r) Cred[((m2 * 4 + k4) * 4 + r) * 64 + lane] = qacc[r];
      __syncthreads();
      {  // combine -> qbl (local q staging); tid<64 also reduce TRED
        const int col2 = tid & 15, b2 = tid >> 4;
        const int m2r = b2 >> 4, bm = b2 & 15, l = (bm >> 2) * 16 + col2, r = bm & 3;
        float s = 0.f;
#pragma unroll
        for (int kk = 0; kk < 4; ++kk) s += Cred[((m2r * 4 + kk) * 4 + r) * 64 + l];
        qbl[b2 * 16 + col2] = s;
        if (tid < 64) {
          float t = redT[tid] + redT[tid + 64] + redT[tid + 128] + redT[tid + 192];
#pragma unroll
          for (int off = 32; off > 0; off >>= 1) t += __shfl_xor(t, off);
          if (tid == 0) scal[3] = t;
        }
      }
      __syncthreads();
      // tagged publishes: 6 chunks per batch for this block's 16 cols + TRED
      if (tid < 192) {
        const int b2 = tid / 6, k = tid % 6, c0 = k * 3;
        u32x4 v;
        v[0] = __float_as_uint(qbl[b2 * 16 + c0]);
        v[1] = (k < 5) ? __float_as_uint(qbl[b2 * 16 + c0 + 1]) : 0u;
        v[2] = (k < 5) ? __float_as_uint(qbl[b2 * 16 + c0 + 2]) : 0u;
        v[3] = tag;
        STSC4(qt + ((size_t)(b2 * 32 + bid) * 6 + k) * 4, v);
      } else if (tid == 192) {
        u32x4 v;
        v[0] = __float_as_uint(scal[3]); v[1] = 0u; v[2] = 0u; v[3] = tag;
        STSC4(trc + (size_t)bid * 4, v);
      }
      __syncthreads();  // qbl reused below by consumer staging
    }

    // out-write moved here: its HBM ack drains at the end-of-step barrier
    if (j >= 1 && bid < NB && tid < NS)
      out[((size_t)bid * NT + (j - 1)) * NS + tid] = ld_cg(&w_prev[bid * NS + tid]) * swinv_l[bid];

    // ---- conv precompute: D = wcomb·(e_prev/SE) + key (overlaps producers)
    f32x4 bacc[2][4];
    {
      const float invSE = 1.f / scal[0];
#pragma unroll
      for (int nt = 0; nt < 2; ++nt) {
        const int base = nt * 16 + col + quad * 8;
        short8 bv;
#pragma unroll
        for (int jj = 0; jj < 8; ++jj) bv[jj] = f2bf(alignl[base + jj] * invSE);
#pragma unroll
        for (int t = 0; t < 4; ++t) {
          f32x4 acc;
          acc[0] = __uint_as_float(keylo[t][nt] << 16);
          acc[1] = __uint_as_float(keylo[t][nt] & 0xffff0000u);
          acc[2] = __uint_as_float(keyhi[t][nt] << 16);
          acc[3] = __uint_as_float(keyhi[t][nt] & 0xffff0000u);
          bacc[nt][t] = MF(wcA[t], bv, acc);
        }
      }
    }
    // ---- poll tagged q chunks for THIS block's batch (data==detection) ---
    if (tid < 193) {
      const unsigned* pp = (tid < 192)
          ? qt + ((size_t)(pb_b * 32 + tid / 6) * 6 + (tid % 6)) * 4
          : trc + (size_t)pb_b * 4;
      u32x4 v;
      for (;;) {
        LDSC4W(v, pp);
        if (v[3] >= tag) break;
        __builtin_amdgcn_s_sleep(2);
      }
      if (tid < 192) {
        const int g = tid / 6, k = tid % 6, c0 = g * 16 + k * 3;
        qbl[c0] = __uint_as_float(v[0]);
        if (k < 5) {
          qbl[c0 + 1] = __uint_as_float(v[1]);
          qbl[c0 + 2] = __uint_as_float(v[2]);
        }
      } else {
        scal[2] = __uint_as_float(v[0]);
      }
    }
    __syncthreads();

    // ---- B residual ----
    {
      const int b = pb_b, s0v = pb_s0;
      const float invSW = swinv_l[b];
      const float tr = (j == 0) ? 0.5f : fsig(scal[2]);
#pragma unroll
      for (int nt = 0; nt < 2; ++nt) {
        float pe = 0.f;
#pragma unroll
        for (int t = 0; t < 4; ++t) {
          const int c2b = (4 * wv + t) * 16 + quad * 4;
          const f32x4 av = bacc[nt][t];
          pe += wagr[t][0] * ftanh(av[0] + qbl[c2b + 0]);
          pe += wagr[t][1] * ftanh(av[1] + qbl[c2b + 1]);
          pe += wagr[t][2] * ftanh(av[2] + qbl[c2b + 2]);
          pe += wagr[t][3] * ftanh(av[3] + qbl[c2b + 3]);
        }
        pe += __shfl_xor(pe, 16);
        pe += __shfl_xor(pe, 32);
        if (lane < 16) Epart[(nt * 16 + col) * 9 + wv] = pe;
      }
      __syncthreads();
      if (tid < 32) {
        const int sl = tid, s = s0v + sl;
        float Ev = 0.f;
#pragma unroll
        for (int w8 = 0; w8 < 8; ++w8) Ev += Epart[sl * 9 + w8];
        const float ev = (mask[b * NS + s] != 0.f) ? __expf(Ev) : 0.f;
        const float csv = ((1.f - tr) * wl2[sl + 1] + tr * wl2[sl]) * invSW + 1e-7f;
        const float wvv = csv * ev;
        st_cg(&e_cur[b * NS + s], ev);
        st_cg(&w_cur[b * NS + s], wvv);
        wstash[sl] = wvv;
        float se = ev, sw2 = wvv;
#pragma unroll
        for (int off = 16; off > 0; off >>= 1) {
          se += __shfl_down(se, off, 32);
          sw2 += __shfl_down(sw2, off, 32);
        }
        if (sl == 0) { atomicAdd(&se_cur[b], se); atomicAdd(&sw_cur[b], sw2); }
      }
      __syncthreads();
      {  // prevU[b][i] += sum_s w_s * enc16[b,s,i]
        const unsigned short* ep = ENC16 + ((size_t)(b * NS + s0v)) * NI + tid;
        float acc = 0.f;
#pragma unroll 8
        for (int ss = 0; ss < 32; ++ss) acc += wstash[ss] * bfu(ep[(size_t)ss * NI]);
        atomicAdd(&pu_cur[(size_t)b * NI + tid], acc);
      }
    }
    gbarrier(root, flags, ph);  // the single remaining grid barrier
  }

  // epilogue: alpha_{T-1} (parity 1 since 799 is odd)
  if (bid < NB && tid < NS) {
    const float invSW = 1.f / ld_cg(&SWB[NB + bid]);
    out[((size_t)bid * NT + (NT - 1)) * NS + tid] =
        ld_cg(&WBUF[(size_t)NB * NS + bid * NS + tid]) * invSW;
  }
}

// ---------------------------------------------------------------------------
extern "C" void kernel_launch(void* const* d_in, const int* in_sizes, int n_in,
                              void* d_out, int out_size, void* d_ws, size_t ws_size,
                              hipStream_t stream) {
  const float* enc     = (const float*)d_in[0];
  const float* queries = (const float*)d_in[1];
  const float* outputs = (const float*)d_in[2];
  const float* mask    = (const float*)d_in[3];
  const float* w_ih    = (const float*)d_in[4];
  const float* w_hh    = (const float*)d_in[5];
  const float* b_ih    = (const float*)d_in[6];
  const float* b_hh    = (const float*)d_in[7];
  const float* w_q     = (const float*)d_in[8];
  const float* w_loc1  = (const float*)d_in[9];
  const float* w_loc2  = (const float*)d_in[10];
  const float* w_k     = (const float*)d_in[11];
  const float* b_k     = (const float*)d_in[12];
  const float* w_agg   = (const float*)d_in[13];
  const float* w_t1    = (const float*)d_in[14];
  const float* b_t1    = (const float*)d_in[15];
  const float* w_t2    = (const float*)d_in[16];
  float* ws = (float*)d_ws;
  float* out = (float*)d_out;
  (void)in_sizes; (void)n_in; (void)out_size; (void)ws_size;

  k_init<<<dim3(1024), dim3(256), 0, stream>>>(enc, queries, outputs, w_k, w_q, ws);
  k_key<<<dim3(NBLK), dim3(NTHR), 0, stream>>>(enc, b_k, ws);
  k_main<<<dim3(NBLK), dim3(NTHR), 0, stream>>>(enc, mask, w_ih, w_hh, b_ih, b_hh,
                                                w_loc1, w_loc2, w_agg, w_t1,
                                                b_t1, w_t2, ws, out);
}